// Round 13
// baseline (668.706 us; speedup 1.0000x reference)
//
#include <hip/hip_runtime.h>
#include <hip/hip_cooperative_groups.h>
#include <stdint.h>

namespace cg = cooperative_groups;

// Contraction off file-wide: the uncertainty path drives top-k SELECTION ORDER
// and must be bit-identical to the JAX/numpy reference (mul+add, no fma).
#pragma clang fp contract(off)

#define NB    8
#define CCH   19
#define CSTR  20       // ctr row stride (19 ch + 1 pad), 80 B, float4-aligned
#define FCH   256
#define FIN   275
#define KP    288      // K padded to 9*32
#define NPTS  16384
#define NSAMP 49152
#define NIMP  12288
#define NRAND 4096
#define SORT_M 65536
#define CHUNK  8192
#define TP    64       // points per block in fused MFMA head
#define XROW  640      // bytes per xp row. MUST be a multiple of 128: the XOR
                       // swizzle flips byte bits 4-6, so rows must be closed
                       // under ^0x70 (r11's 608 leaked writes into the next row)
#define WBF_OFF (4u << 20)                  // bf16 weights (after keys' 4 MiB)
#define CTR_OFF (4718592u)                  // 4 MiB + 512 KiB: coarse transposed
#define FTR_OFF (8u << 20)                  // transposed features
#define FTR_BYTES (134217728ull / 2)        // 8*16384*256*2 = 64 MiB

typedef __attribute__((ext_vector_type(8))) short bf16x8;
typedef __attribute__((ext_vector_type(4))) float f32x4;

// ---------------- threefry2x32 (exact JAX algorithm) ----------------
__host__ __device__ __forceinline__ uint32_t rotl32(uint32_t v, int r) {
  return (v << r) | (v >> (32 - r));
}

__host__ __device__ __forceinline__ void tf2x32(uint32_t k0, uint32_t k1,
                                                uint32_t x0, uint32_t x1,
                                                uint32_t* o0, uint32_t* o1) {
  const uint32_t ks2 = k0 ^ k1 ^ 0x1BD11BDAu;
  x0 += k0; x1 += k1;
#define TF_R(r) { x0 += x1; x1 = rotl32(x1, (r)); x1 ^= x0; }
  TF_R(13) TF_R(15) TF_R(26) TF_R(6)
  x0 += k1;  x1 += ks2 + 1u;
  TF_R(17) TF_R(29) TF_R(16) TF_R(24)
  x0 += ks2; x1 += k0 + 2u;
  TF_R(13) TF_R(15) TF_R(26) TF_R(6)
  x0 += k0;  x1 += k1 + 3u;
  TF_R(17) TF_R(29) TF_R(16) TF_R(24)
  x0 += k1;  x1 += ks2 + 4u;
  TF_R(13) TF_R(15) TF_R(26) TF_R(6)
  x0 += ks2; x1 += k0 + 5u;
#undef TF_R
  *o0 = x0; *o1 = x1;
}

// partitionable random_bits: bits[i] = o0 ^ o1 of tf(key, (0, i))
__device__ __forceinline__ float u01_at(uint32_t k0, uint32_t k1, uint32_t i) {
  uint32_t o0, o1;
  tf2x32(k0, k1, 0u, i, &o0, &o1);
  const uint32_t b = o0 ^ o1;
  const float f = __uint_as_float((b >> 9) | 0x3f800000u) - 1.0f;
  return fmaxf(0.0f, f);
}

__device__ __forceinline__ unsigned short f2bf(float f) {
  const uint32_t u = __float_as_uint(f);
  return (unsigned short)((u + 0x7fffu + ((u >> 16) & 1u)) >> 16);
}

__device__ __forceinline__ float bf2f(unsigned short h) {
  return __uint_as_float((uint32_t)h << 16);
}

// interp params for the LOGITS path (bf16 tolerance; same formula as exact path)
template <int SZ>
__device__ __forceinline__ void interp(float cx, float cy, int* off, float* wgt) {
  const float X = cx * (float)SZ - 0.5f, Y = cy * (float)SZ - 0.5f;
  const float x0f = floorf(X), y0f = floorf(Y);
  const float fx = X - x0f, fy = Y - y0f;
  const float wx0 = 1.0f - fx, wy0 = 1.0f - fy;
  const int x0 = (int)x0f, y0 = (int)y0f;
  const int x0c = min(max(x0, 0), SZ - 1), x1c = min(max(x0 + 1, 0), SZ - 1);
  const int y0c = min(max(y0, 0), SZ - 1), y1c = min(max(y0 + 1, 0), SZ - 1);
  const bool vx0 = (x0 >= 0) & (x0 <= SZ - 1), vx1 = (x0 >= -1) & (x0 <= SZ - 2);
  const bool vy0 = (y0 >= 0) & (y0 <= SZ - 1), vy1 = (y0 >= -1) & (y0 <= SZ - 2);
  off[0] = y0c * SZ + x0c; wgt[0] = (vy0 & vx0) ? wy0 * wx0 : 0.0f;
  off[1] = y0c * SZ + x1c; wgt[1] = (vy0 & vx1) ? wy0 * fx  : 0.0f;
  off[2] = y1c * SZ + x0c; wgt[2] = (vy1 & vx0) ? fy  * wx0 : 0.0f;
  off[3] = y1c * SZ + x1c; wgt[3] = (vy1 & vx1) ? fy  * fx  : 0.0f;
}

// ---- features transpose tile helpers (tile = 64ch x 64px, tt in [0,256)) ----
__device__ __forceinline__ void ftr_tile_load(const float* __restrict__ feats,
                                              int ti, int tt,
                                              unsigned short (*tile)[66]) {
  const int nn = ti >> 10, ct = (ti >> 8) & 3, pt = ti & 255;
  const int c0 = ct * 64, p0 = pt * 64;
  const float* src = feats + ((size_t)nn << 22);
#pragma unroll 4
  for (int k = 0; k < 16; ++k) {
    const int c = 4 * k + (tt >> 6);
    const int p = tt & 63;
    tile[p][c] = f2bf(src[((size_t)(c0 + c) << 14) + p0 + p]);
  }
}

__device__ __forceinline__ void ftr_tile_store(unsigned short* __restrict__ ftr,
                                               int ti, int tt,
                                               unsigned short (*tile)[66]) {
  const int nn = ti >> 10, ct = (ti >> 8) & 3, pt = ti & 255;
  const int c0 = ct * 64, p0 = pt * 64;
  const int p = tt >> 2, q = tt & 3;
  const int cb = q * 16;
  uint32_t w[8];
#pragma unroll
  for (int m = 0; m < 8; ++m)
    w[m] = (uint32_t)tile[p][cb + 2 * m] | ((uint32_t)tile[p][cb + 2 * m + 1] << 16);
  unsigned short* dst = ftr + ((((size_t)nn << 14) + p0 + p) << 8) + c0 + cb;
  *(uint4*)(dst)     = make_uint4(w[0], w[1], w[2], w[3]);
  *(uint4*)(dst + 8) = make_uint4(w[4], w[5], w[6], w[7]);
}

// ---- prep: ctr transpose [0,128) | weights [128,1028) | out0 copy [1028,1636) ----
__global__ __launch_bounds__(256) void prep(
    const float* __restrict__ coarse, float* __restrict__ ctr,
    const float* __restrict__ w0, const float* __restrict__ w1,
    const float* __restrict__ w2, const float* __restrict__ wpw,
    unsigned short* __restrict__ wbf, unsigned short* __restrict__ wpb,
    float* __restrict__ out0) {
  __shared__ float tile[CCH][257];
  const int b = blockIdx.x, t = threadIdx.x;
  if (b < 128) {
    const int nn = b >> 4, px0 = (b & 15) * 256;
    const float* src = coarse + (size_t)nn * (CCH * 4096) + px0;
#pragma unroll
    for (int c = 0; c < CCH; ++c) tile[c][t] = src[c * 4096 + t];
    __syncthreads();
    float v[CSTR];
#pragma unroll
    for (int c = 0; c < CCH; ++c) v[c] = tile[c][t];
    v[19] = 0.0f;
    float* dst = ctr + ((size_t)(nn << 12) + px0 + t) * CSTR;
#pragma unroll
    for (int k = 0; k < 5; ++k) {
      f32x4 x; x[0] = v[4*k]; x[1] = v[4*k+1]; x[2] = v[4*k+2]; x[3] = v[4*k+3];
      *(f32x4*)(dst + 4 * k) = x;
    }
  } else if (b < 1028) {
    const int i = (b - 128) * 256 + t;
    if (i < 3 * 256 * KP) {
      const int L = i / (256 * KP);
      const int rem = i - L * (256 * KP);
      const int o = rem / KP, k = rem - o * KP;
      const float* W = (L == 0) ? w0 : (L == 1) ? w1 : w2;
      wbf[i] = (k < FIN) ? f2bf(W[o * FIN + k]) : (unsigned short)0;
    } else {
      const int j = i - 3 * 256 * KP;
      const int o = j / KP, k = j - o * KP;
      wpb[j] = (o < CCH && k < FIN) ? f2bf(wpw[o * FIN + k]) : (unsigned short)0;
    }
  } else {
    // coarse passthrough: 155648 float4 = 622592 f32 (exact)
    const int i4 = (b - 1028) * 256 + t;
    ((float4*)out0)[i4] = ((const float4*)coarse)[i4];
  }
}

// ---------------- cooperative pipeline: unc -> full sort -> coords ----------------
// 256 blocks x 1024 thr, co-resident (1 block/CU). Blocks [0,64): the bitonic
// sort phases (same bodies as the r8-r11 dispatch chain). Blocks [64,256):
// feature-transpose tile quads, spread across phases so the HBM-bound
// transpose hides under the sort's low-parallelism critical path.
__device__ __forceinline__ void unc_slot(const float* __restrict__ ctr,
                                         unsigned long long* __restrict__ keys,
                                         uint32_t k1a, uint32_t k1b, int tid) {
  const int nn = tid >> 16, sIdx = tid & (SORT_M - 1);
  if (sIdx >= NSAMP) { keys[tid] = 0xFFFFFFFFFFFFFFFFull; return; }
  const uint32_t ci = (uint32_t)(((unsigned)nn * NSAMP + (unsigned)sIdx) * 2);
  const float cx = u01_at(k1a, k1b, ci);
  const float cy = u01_at(k1a, k1b, ci + 1);
  const float X = cx * 64.0f - 0.5f, Y = cy * 64.0f - 0.5f;
  const float x0f = floorf(X), y0f = floorf(Y);
  const float fx = X - x0f, fy = Y - y0f;
  const float wx0 = 1.0f - fx, wy0 = 1.0f - fy;
  const int x0 = (int)x0f, y0 = (int)y0f;
  const int x0c = min(max(x0, 0), 63), x1c = min(max(x0 + 1, 0), 63);
  const int y0c = min(max(y0, 0), 63), y1c = min(max(y0 + 1, 0), 63);
  const bool vx0 = (x0 >= 0) & (x0 <= 63), vx1 = (x0 >= -1) & (x0 <= 62);
  const bool vy0 = (y0 >= 0) & (y0 <= 63), vy1 = (y0 >= -1) & (y0 <= 62);
  const float w00 = (vy0 & vx0) ? wy0 * wx0 : 0.0f;
  const float w01 = (vy0 & vx1) ? wy0 * fx  : 0.0f;
  const float w10 = (vy1 & vx0) ? fy  * wx0 : 0.0f;
  const float w11 = (vy1 & vx1) ? fy  * fx  : 0.0f;
  const float* rb = ctr + ((size_t)nn << 12) * CSTR;
  const float* r0 = rb + (size_t)(y0c * 64 + x0c) * CSTR;
  const float* r1 = rb + (size_t)(y0c * 64 + x1c) * CSTR;
  const float* r2 = rb + (size_t)(y1c * 64 + x0c) * CSTR;
  const float* r3 = rb + (size_t)(y1c * 64 + x1c) * CSTR;
  float m1 = -3.402823466e38f, m2 = -3.402823466e38f;
#pragma unroll
  for (int k = 0; k < 5; ++k) {
    const f32x4 x0v = *(const f32x4*)(r0 + 4 * k);
    const f32x4 x1v = *(const f32x4*)(r1 + 4 * k);
    const f32x4 x2v = *(const f32x4*)(r2 + 4 * k);
    const f32x4 x3v = *(const f32x4*)(r3 + 4 * k);
#pragma unroll
    for (int e = 0; e < 4; ++e) {
      const int c = 4 * k + e;
      if (c < CCH) {
        // EXACT left-assoc mul/add (contract off) — selection-order critical
        const float v = ((x0v[e] * w00 + x1v[e] * w01) + x2v[e] * w10) + x3v[e] * w11;
        if (v > m1) { m2 = m1; m1 = v; } else if (v > m2) { m2 = v; }
      }
    }
  }
  const float unc = m2 - m1;
  const uint32_t b = __float_as_uint(unc);
  const uint32_t asc = (b & 0x80000000u) ? ~b : (b | 0x80000000u);
  keys[tid] = ((unsigned long long)(~asc) << 32) | (uint32_t)sIdx;
}

__device__ __forceinline__ void cx_step(unsigned long long* __restrict__ keys,
                                        int k, int j, int shift, int idx) {
  const int bb = idx >> shift, pid = idx & ((1 << shift) - 1);
  const int i = ((pid & ~(j - 1)) << 1) | (pid & (j - 1));
  const int l = i | j;
  const bool up = ((i & k) == 0);
  unsigned long long* a = keys + ((size_t)bb << 16);
  const unsigned long long x = a[i], y = a[l];
  if ((x > y) == up) { a[i] = y; a[l] = x; }
}

__global__ __launch_bounds__(1024) void coop_pipe(
    const float* __restrict__ ctr, unsigned long long* __restrict__ keys,
    const float* __restrict__ feats, unsigned short* __restrict__ ftr,
    float* __restrict__ outc,
    uint32_t k1a, uint32_t k1b, uint32_t k2a, uint32_t k2b, int use_tr) {
  __shared__ unsigned long long sbuf[CHUNK];   // 64 KiB; aliased by transpose
  const int b = blockIdx.x, t = threadIdx.x;
  cg::grid_group grid = cg::this_grid();

  // ---- P0: uncertainty keys (all blocks; 2 slots/thread) ----
  {
    const int gid = b * 1024 + t;
    unc_slot(ctr, keys, k1a, k1b, gid * 2);
    unc_slot(ctr, keys, k1a, k1b, gid * 2 + 1);
  }
  grid.sync();

  for (int p = 1; p <= 10; ++p) {
    if (b < 64) {
      unsigned long long* a = keys + (size_t)b * CHUNK;
      const unsigned gbase = (unsigned)(b * CHUNK) & (SORT_M - 1);
      if (p == 1) {
        // local bitonic sort of chunk b
        for (int i = t; i < CHUNK; i += 1024) sbuf[i] = a[i];
        __syncthreads();
        for (int k = 2; k <= CHUNK; k <<= 1) {
          for (int j = k >> 1; j > 0; j >>= 1) {
            for (int pid = t; pid < CHUNK / 2; pid += 1024) {
              const int i = ((pid & ~(j - 1)) << 1) | (pid & (j - 1));
              const int l = i | j;
              const bool up = (((gbase + i) & k) == 0);
              const unsigned long long x = sbuf[i], y = sbuf[l];
              if ((x > y) == up) { sbuf[i] = y; sbuf[l] = x; }
            }
            __syncthreads();
          }
        }
        for (int i = t; i < CHUNK; i += 1024) a[i] = sbuf[i];
      } else if (p == 3 || p == 6) {
        // finish: local j<=4096 merge of chunk b for k = 16384 / 32768
        const int k = (p == 3) ? 16384 : 32768;
        for (int i = t; i < CHUNK; i += 1024) sbuf[i] = a[i];
        __syncthreads();
        const bool up = ((gbase & k) == 0);
        for (int j = CHUNK >> 1; j > 0; j >>= 1) {
          for (int pid = t; pid < CHUNK / 2; pid += 1024) {
            const int i = ((pid & ~(j - 1)) << 1) | (pid & (j - 1));
            const int l = i | j;
            const unsigned long long x = sbuf[i], y = sbuf[l];
            if ((x > y) == up) { sbuf[i] = y; sbuf[l] = x; }
          }
          __syncthreads();
        }
        for (int i = t; i < CHUNK; i += 1024) a[i] = sbuf[i];
      } else if (p == 2 || p == 4 || p == 5 || p == 7) {
        // full-width global steps: 262144 pairs over 65536 threads (4 each)
        int k, j;
        if (p == 2)      { k = 16384; j = 8192;  }
        else if (p == 4) { k = 32768; j = 16384; }
        else if (p == 5) { k = 32768; j = 8192;  }
        else             { k = 65536; j = 32768; }
        const int base = b * 1024 + t;
#pragma unroll
        for (int w = 0; w < 4; ++w)
          cx_step(keys, k, j, 15, base + (w << 16));
      } else if (p == 8) {
        // k=65536 j=16384, low half only (131072 pairs)
        const int base = b * 1024 + t;
        cx_step(keys, 65536, 16384, 14, base);
        cx_step(keys, 65536, 16384, 14, base + 65536);
      } else if (p == 9) {
        // k=65536 j=8192, low quarter only (65536 pairs)
        cx_step(keys, 65536, 8192, 13, b * 1024 + t);
      } else {  // p == 10: finlow + coords (blocks 0..15)
        if (b < 16) {
          const int nn = b >> 1, half = b & 1;
          const unsigned long long* src = keys + ((size_t)nn << 16) + half * CHUNK;
          for (int i = t; i < CHUNK; i += 1024) sbuf[i] = src[i];
          __syncthreads();
          for (int j = CHUNK >> 1; j > 0; j >>= 1) {   // ascending
            for (int pid = t; pid < CHUNK / 2; pid += 1024) {
              const int i = ((pid & ~(j - 1)) << 1) | (pid & (j - 1));
              const int l = i | j;
              const unsigned long long x = sbuf[i], y = sbuf[l];
              if (x > y) { sbuf[i] = y; sbuf[l] = x; }
            }
            __syncthreads();
          }
          const int pb = half * CHUNK;
          for (int q = t; q < CHUNK; q += 1024) {
            const int pp = pb + q;
            float cx, cy;
            if (pp < NIMP) {
              const unsigned idx = (unsigned)(sbuf[q] & 0xFFFFFFFFu);
              const uint32_t ci = ((unsigned)nn * NSAMP + idx) * 2;
              cx = u01_at(k1a, k1b, ci);
              cy = u01_at(k1a, k1b, ci + 1);
            } else {
              const uint32_t ri = ((unsigned)nn * NRAND + (unsigned)(pp - NIMP)) * 2;
              cx = u01_at(k2a, k2b, ri);
              cy = u01_at(k2a, k2b, ri + 1);
            }
            float* o = outc + (((size_t)nn << 14) + pp) * 2;
            o[0] = cx; o[1] = cy;
          }
        }
      }
    } else if (use_tr) {
      // transpose quads: block handles quad q = (b-64) + 192*j, 4 tiles each
      for (int j = (p - 1) * 11 / 10; j < p * 11 / 10; ++j) {
        const int q = (b - 64) + 192 * j;
        const int ti = q * 4 + (t >> 8);
        unsigned short (*tp)[66] =
            (unsigned short (*)[66])((char*)sbuf + (size_t)(t >> 8) * (64 * 66 * 2));
        if (ti < 8192) ftr_tile_load(feats, ti, t & 255, tp);
        __syncthreads();
        if (ti < 8192) ftr_tile_store(ftr, ti, t & 255, tp);
        __syncthreads();
      }
    }
    if (p < 10) grid.sync();
  }
}

// ---------------- fused sample + bf16-MFMA MLP + head (r10 proven, XROW 640) ----
template <int USE_TR>
__global__ __launch_bounds__(512, 4) void fused_mfma(
    const float* __restrict__ coarse, const float* __restrict__ feats,
    const unsigned short* __restrict__ ftr, const float* __restrict__ ctr,
    const float* __restrict__ b0, const float* __restrict__ b1,
    const float* __restrict__ b2, const float* __restrict__ bp,
    const unsigned short* __restrict__ wbf, const unsigned short* __restrict__ wpb,
    const float* __restrict__ pc, float* __restrict__ outl) {
  __shared__ __align__(16) unsigned short xp[TP * (XROW / 2)];   // 40960 B

  const int t = threadIdx.x;
  // XCD swizzle: XCD x serves batch x's ftr slab (8 MB vs 4 MB L2).
  const int bid = ((int)blockIdx.x & 7) * 256 + ((int)blockIdx.x >> 3);
  const int nn = bid >> 8;
  const int pbase = (bid & 255) * TP;

  int offF[4]; float wgtF[4];     // fine interp of point t>>3
  int offC[4]; float wgtC[4];     // coarse interp of point t&63
  int offFc[4]; float wgtFc[4];   // fine interp of point t&63 (fallback only)
  {
    const float2 c = *(const float2*)(pc + ((size_t)nn * NPTS + pbase + (t >> 3)) * 2);
    interp<128>(c.x, c.y, offF, wgtF);
  }
  {
    const float2 c = *(const float2*)(pc + ((size_t)nn * NPTS + pbase + (t & 63)) * 2);
    interp<64>(c.x, c.y, offC, wgtC);
    if (!USE_TR) interp<128>(c.x, c.y, offFc, wgtFc);
  }

  if (USE_TR) {
    // ---- fine gather from transposed bf16: 8 thr/point, 32 ch each ----
    const int p = t >> 3, q = t & 7;
    const unsigned short* base = ftr + ((size_t)nn << 22) + q * 32;
    const unsigned short* n0 = base + ((size_t)offF[0] << 8);
    const unsigned short* n1 = base + ((size_t)offF[1] << 8);
    const unsigned short* n2 = base + ((size_t)offF[2] << 8);
    const unsigned short* n3 = base + ((size_t)offF[3] << 8);
    const float g0 = wgtF[0], g1 = wgtF[1], g2 = wgtF[2], g3 = wgtF[3];
    const unsigned swzp = (unsigned)(p & 7) << 4;
#pragma unroll
    for (int m = 0; m < 4; ++m) {
      const bf16x8 a = *(const bf16x8*)(n0 + m * 8);
      const bf16x8 bq = *(const bf16x8*)(n1 + m * 8);
      const bf16x8 c = *(const bf16x8*)(n2 + m * 8);
      const bf16x8 d = *(const bf16x8*)(n3 + m * 8);
      uint32_t u[4];
#pragma unroll
      for (int e = 0; e < 4; ++e) {
        float v0 = fmaf(bf2f((unsigned short)a[2 * e]), g0,
                   fmaf(bf2f((unsigned short)bq[2 * e]), g1,
                   fmaf(bf2f((unsigned short)c[2 * e]), g2,
                        bf2f((unsigned short)d[2 * e]) * g3)));
        float v1 = fmaf(bf2f((unsigned short)a[2 * e + 1]), g0,
                   fmaf(bf2f((unsigned short)bq[2 * e + 1]), g1,
                   fmaf(bf2f((unsigned short)c[2 * e + 1]), g2,
                        bf2f((unsigned short)d[2 * e + 1]) * g3)));
        u[e] = (uint32_t)f2bf(v0) | ((uint32_t)f2bf(v1) << 16);
      }
      *(uint4*)((char*)xp + p * XROW + (((unsigned)((q * 32 + m * 8) * 2)) ^ swzp)) =
          make_uint4(u[0], u[1], u[2], u[3]);
    }
    // ---- coarse channels 256..287 from ctr: one thread per point ----
    if (t < TP) {
      const int pp = t;
      const float* rb = ctr + ((size_t)nn << 12) * CSTR;
      const float* r0 = rb + (size_t)offC[0] * CSTR;
      const float* r1 = rb + (size_t)offC[1] * CSTR;
      const float* r2 = rb + (size_t)offC[2] * CSTR;
      const float* r3 = rb + (size_t)offC[3] * CSTR;
      const float h0 = wgtC[0], h1 = wgtC[1], h2 = wgtC[2], h3 = wgtC[3];
      unsigned short hs[32];
#pragma unroll
      for (int k = 0; k < 5; ++k) {
        const f32x4 x0v = *(const f32x4*)(r0 + 4 * k);
        const f32x4 x1v = *(const f32x4*)(r1 + 4 * k);
        const f32x4 x2v = *(const f32x4*)(r2 + 4 * k);
        const f32x4 x3v = *(const f32x4*)(r3 + 4 * k);
#pragma unroll
        for (int e = 0; e < 4; ++e) {
          const int c = 4 * k + e;
          if (c < CCH)
            hs[c] = f2bf(fmaf(x0v[e], h0, fmaf(x1v[e], h1,
                         fmaf(x2v[e], h2, x3v[e] * h3))));
        }
      }
#pragma unroll
      for (int c = CCH; c < 32; ++c) hs[c] = 0;
      const unsigned swzc = (unsigned)(pp & 7) << 4;
#pragma unroll
      for (int k = 0; k < 4; ++k) {
        uint4 u;
        u.x = (uint32_t)hs[8*k]   | ((uint32_t)hs[8*k+1] << 16);
        u.y = (uint32_t)hs[8*k+2] | ((uint32_t)hs[8*k+3] << 16);
        u.z = (uint32_t)hs[8*k+4] | ((uint32_t)hs[8*k+5] << 16);
        u.w = (uint32_t)hs[8*k+6] | ((uint32_t)hs[8*k+7] << 16);
        *(uint4*)((char*)xp + pp * XROW + (((unsigned)(512 + 16 * k)) ^ swzc)) = u;
      }
    }
  } else {
    // ---- fallback: scalar gather of all channels from original layouts ----
    for (int i = t; i < (KP / 2) * TP; i += 512) {
      const int p = i & (TP - 1);
      const int c0 = (i >> 6) * 2;
      float v0 = 0.0f, v1 = 0.0f;
      if (c0 < FCH) {
        const float* fb0 = feats + ((size_t)nn << 22) + ((size_t)c0 << 14);
        const float* fb1 = fb0 + 16384;
        v0 = ((fb0[offFc[0]] * wgtFc[0] + fb0[offFc[1]] * wgtFc[1])
             + fb0[offFc[2]] * wgtFc[2]) + fb0[offFc[3]] * wgtFc[3];
        v1 = ((fb1[offFc[0]] * wgtFc[0] + fb1[offFc[1]] * wgtFc[1])
             + fb1[offFc[2]] * wgtFc[2]) + fb1[offFc[3]] * wgtFc[3];
      } else if (c0 < FIN) {
        const float* cb0 = coarse + (size_t)nn * (CCH * 4096) + (size_t)(c0 - FCH) * 4096;
        v0 = ((cb0[offC[0]] * wgtC[0] + cb0[offC[1]] * wgtC[1])
             + cb0[offC[2]] * wgtC[2]) + cb0[offC[3]] * wgtC[3];
        if (c0 + 1 < FIN) {
          const float* cb1 = cb0 + 4096;
          v1 = ((cb1[offC[0]] * wgtC[0] + cb1[offC[1]] * wgtC[1])
               + cb1[offC[2]] * wgtC[2]) + cb1[offC[3]] * wgtC[3];
        }
      }
      const uint32_t u = (uint32_t)f2bf(v0) | ((uint32_t)f2bf(v1) << 16);
      *(uint32_t*)((char*)xp + p * XROW + (((unsigned)(c0 * 2)) ^ ((unsigned)(p & 7) << 4))) = u;
    }
  }

  const int lane = t & 63, wave = t >> 6;
  const int wm = wave & 3, wn = wave >> 2;
  const int l15 = lane & 15, g = lane >> 4;
  const unsigned swz = (unsigned)(l15 & 7) << 4;
  const char* xpB = (const char*)xp;

#pragma unroll    // static L => weight/bias pointers resolved at compile time
  for (int L = 0; L < 3; ++L) {
    __syncthreads();   // xp inputs visible (gather for L=0, epilogue for L>0)
    const float* Bv = (L == 0) ? b0 : (L == 1) ? b1 : b2;
    const unsigned short* wL = wbf + (size_t)L * (256 * KP);
    const unsigned short* wbase = wL + (size_t)(wm * 64 + l15) * KP + g * 8;

    f32x4 acc[4][2];
#pragma unroll
    for (int mt = 0; mt < 4; ++mt)
#pragma unroll
      for (int nt = 0; nt < 2; ++nt) acc[mt][nt] = (f32x4)(0.0f);

    // 1-deep weight prefetch: a-regs for ks+1 issued during ks's MFMAs.
    bf16x8 a0 = *(const bf16x8*)(wbase + 0 * 16 * KP);
    bf16x8 a1 = *(const bf16x8*)(wbase + 1 * 16 * KP);
    bf16x8 a2 = *(const bf16x8*)(wbase + 2 * 16 * KP);
    bf16x8 a3 = *(const bf16x8*)(wbase + 3 * 16 * KP);
    for (int ks = 0; ks < 9; ++ks) {
      const bf16x8 c0v = a0, c1v = a1, c2v = a2, c3v = a3;
      if (ks < 8) {
        a0 = *(const bf16x8*)(wbase + 0 * 16 * KP + (ks + 1) * 32);
        a1 = *(const bf16x8*)(wbase + 1 * 16 * KP + (ks + 1) * 32);
        a2 = *(const bf16x8*)(wbase + 2 * 16 * KP + (ks + 1) * 32);
        a3 = *(const bf16x8*)(wbase + 3 * 16 * KP + (ks + 1) * 32);
      }
      const unsigned kb = (unsigned)(ks * 64 + g * 16) ^ swz;
      const bf16x8 q0 = *(const bf16x8*)(xpB + (wn * 32 + 0 + l15) * XROW + kb);
      const bf16x8 q1 = *(const bf16x8*)(xpB + (wn * 32 + 16 + l15) * XROW + kb);
      acc[0][0] = __builtin_amdgcn_mfma_f32_16x16x32_bf16(c0v, q0, acc[0][0], 0, 0, 0);
      acc[1][0] = __builtin_amdgcn_mfma_f32_16x16x32_bf16(c1v, q0, acc[1][0], 0, 0, 0);
      acc[2][0] = __builtin_amdgcn_mfma_f32_16x16x32_bf16(c2v, q0, acc[2][0], 0, 0, 0);
      acc[3][0] = __builtin_amdgcn_mfma_f32_16x16x32_bf16(c3v, q0, acc[3][0], 0, 0, 0);
      acc[0][1] = __builtin_amdgcn_mfma_f32_16x16x32_bf16(c0v, q1, acc[0][1], 0, 0, 0);
      acc[1][1] = __builtin_amdgcn_mfma_f32_16x16x32_bf16(c1v, q1, acc[1][1], 0, 0, 0);
      acc[2][1] = __builtin_amdgcn_mfma_f32_16x16x32_bf16(c2v, q1, acc[2][1], 0, 0, 0);
      acc[3][1] = __builtin_amdgcn_mfma_f32_16x16x32_bf16(c3v, q1, acc[3][1], 0, 0, 0);
    }
    __syncthreads();   // all reads of xp done before overwrite

#pragma unroll
    for (int mt = 0; mt < 4; ++mt) {
      const int ch0 = wm * 64 + mt * 16 + (g << 2);
      const float4 bv = *(const float4*)(Bv + ch0);
#pragma unroll
      for (int nt = 0; nt < 2; ++nt) {
        const int p = wn * 32 + nt * 16 + l15;
        const f32x4 v = acc[mt][nt];
        const unsigned short h0 = f2bf(fmaxf(v[0] + bv.x, 0.0f));
        const unsigned short h1 = f2bf(fmaxf(v[1] + bv.y, 0.0f));
        const unsigned short h2 = f2bf(fmaxf(v[2] + bv.z, 0.0f));
        const unsigned short h3 = f2bf(fmaxf(v[3] + bv.w, 0.0f));
        uint2 u;
        u.x = (uint32_t)h0 | ((uint32_t)h1 << 16);
        u.y = (uint32_t)h2 | ((uint32_t)h3 << 16);
        *(uint2*)((char*)xp + p * XROW + (((unsigned)(ch0 * 2)) ^ swz)) = u;
      }
    }
  }
  __syncthreads();   // layer-2 output (head input) visible

  // ---- head: 8 (mt,nt) pairs, one per wave: mt = w>>2 (0..1), nt = w&3 ----
  const int hmt = wave >> 2, hnt = wave & 3;
  const unsigned short* hbase = wpb + (size_t)(hmt * 16 + l15) * KP + g * 8;
  f32x4 hacc = (f32x4)(0.0f);
  for (int ks = 0; ks < 9; ++ks) {
    const unsigned kb = (unsigned)(ks * 64 + g * 16) ^ swz;
    const bf16x8 ha = *(const bf16x8*)(hbase + ks * 32);
    const bf16x8 hb = *(const bf16x8*)(xpB + (hnt * 16 + l15) * XROW + kb);
    hacc = __builtin_amdgcn_mfma_f32_16x16x32_bf16(ha, hb, hacc, 0, 0, 0);
  }
  const int p = pbase + hnt * 16 + l15;
#pragma unroll
  for (int j = 0; j < 4; ++j) {
    const int ch = hmt * 16 + (g << 2) + j;
    if (ch < CCH)
      outl[((size_t)nn * CCH + ch) * NPTS + p] = hacc[j] + bp[ch];
  }
}

// ---------------- launcher ----------------
extern "C" void kernel_launch(void* const* d_in, const int* in_sizes, int n_in,
                              void* d_out, int out_size, void* d_ws, size_t ws_size,
                              hipStream_t stream) {
  const float* coarse = (const float*)d_in[0];
  const float* feats  = (const float*)d_in[1];
  const float* w0 = (const float*)d_in[2]; const float* b0 = (const float*)d_in[3];
  const float* w1 = (const float*)d_in[4]; const float* b1 = (const float*)d_in[5];
  const float* w2 = (const float*)d_in[6]; const float* b2 = (const float*)d_in[7];
  const float* wp = (const float*)d_in[8]; const float* bp = (const float*)d_in[9];

  float* out0 = (float*)d_out;
  float* outL = out0 + 622592;
  float* outC = outL + 2490368;

  unsigned long long* keys = (unsigned long long*)d_ws;            // 4 MiB
  unsigned short* wbf = (unsigned short*)((char*)d_ws + WBF_OFF);  // 450 KiB
  unsigned short* wpb = wbf + 3 * 256 * KP;
  float* ctr = (float*)((char*)d_ws + CTR_OFF);                    // 2.5 MiB
  unsigned short* ftr = (unsigned short*)((char*)d_ws + FTR_OFF);  // 64 MiB
  int use_tr = (ws_size >= (size_t)FTR_OFF + FTR_BYTES) ? 1 : 0;

  // host-side split of jax.random.key(7) = (0,7): key_i = tf(key, (0,i))
  uint32_t k1a, k1b, k2a, k2b;
  tf2x32(0u, 7u, 0u, 0u, &k1a, &k1b);
  tf2x32(0u, 7u, 0u, 1u, &k2a, &k2b);

  // ctr transpose + weight convert + out0 passthrough (one dispatch)
  prep<<<1636, 256, 0, stream>>>(coarse, ctr, w0, w1, w2, wp, wbf, wpb, out0);

  // unc -> full bitonic sort -> coords, with feature-transpose riding along,
  // all inside ONE cooperative dispatch (grid.sync between phases).
  const float* ctr_c = ctr;
  const float* feats_c = feats;
  void* cargs[] = {(void*)&ctr_c, (void*)&keys, (void*)&feats_c, (void*)&ftr,
                   (void*)&outC, (void*)&k1a, (void*)&k1b, (void*)&k2a,
                   (void*)&k2b, (void*)&use_tr};
  hipLaunchCooperativeKernel((void*)coop_pipe, dim3(256), dim3(1024),
                             cargs, 0, stream);

  if (use_tr)
    fused_mfma<1><<<2048, 512, 0, stream>>>(coarse, feats, ftr, ctr, b0, b1, b2,
                                            bp, wbf, wpb, outC, outL);
  else
    fused_mfma<0><<<2048, 512, 0, stream>>>(coarse, feats, ftr, ctr, b0, b1, b2,
                                            bp, wbf, wpb, outC, outL);
}

// Round 14
// 357.640 us; speedup vs baseline: 1.8698x; 1.8698x over previous
//
#include <hip/hip_runtime.h>
#include <stdint.h>

// Contraction off file-wide: the uncertainty path drives top-k SELECTION ORDER
// and must be bit-identical to the JAX/numpy reference (mul+add, no fma).
#pragma clang fp contract(off)

#define NB    8
#define CCH   19
#define CSTR  20       // ctr row stride (19 ch + 1 pad), 80 B, float4-aligned
#define FCH   256
#define FIN   275
#define KP    288      // K padded to 9*32
#define NPTS  16384
#define NSAMP 49152
#define NIMP  12288
#define NRAND 4096
#define SORT_M 65536
#define CHUNK  8192
#define TP    64       // points per block in fused MFMA head
#define XROW  640      // bytes per xp row. MUST be a multiple of 128: the XOR
                       // swizzle flips byte bits 4-6, so rows must be closed
                       // under ^0x70 (r11's 608 leaked writes into the next row)
#define WBF_OFF (4u << 20)                  // bf16 weights (after keys' 4 MiB)
#define CTR_OFF (4718592u)                  // 4 MiB + 512 KiB: coarse transposed
#define FTR_OFF (8u << 20)                  // transposed features
#define FTR_BYTES (134217728ull / 2)        // 8*16384*256*2 = 64 MiB

// NOTE (r13 lesson, banked): hipLaunchCooperativeKernel grid.sync() on MI355X
// costs ~45us/sync (device-scope fence across 8 non-coherent XCD L2s) — a
// 10-phase coop pipeline ran 2.8x SLOWER than the equivalent dispatch chain.
// Dispatch boundaries are the cheap sync on multi-XCD CDNA.

typedef __attribute__((ext_vector_type(8))) short bf16x8;
typedef __attribute__((ext_vector_type(4))) float f32x4;

// ---------------- threefry2x32 (exact JAX algorithm) ----------------
__host__ __device__ __forceinline__ uint32_t rotl32(uint32_t v, int r) {
  return (v << r) | (v >> (32 - r));
}

__host__ __device__ __forceinline__ void tf2x32(uint32_t k0, uint32_t k1,
                                                uint32_t x0, uint32_t x1,
                                                uint32_t* o0, uint32_t* o1) {
  const uint32_t ks2 = k0 ^ k1 ^ 0x1BD11BDAu;
  x0 += k0; x1 += k1;
#define TF_R(r) { x0 += x1; x1 = rotl32(x1, (r)); x1 ^= x0; }
  TF_R(13) TF_R(15) TF_R(26) TF_R(6)
  x0 += k1;  x1 += ks2 + 1u;
  TF_R(17) TF_R(29) TF_R(16) TF_R(24)
  x0 += ks2; x1 += k0 + 2u;
  TF_R(13) TF_R(15) TF_R(26) TF_R(6)
  x0 += k0;  x1 += k1 + 3u;
  TF_R(17) TF_R(29) TF_R(16) TF_R(24)
  x0 += k1;  x1 += ks2 + 4u;
  TF_R(13) TF_R(15) TF_R(26) TF_R(6)
  x0 += ks2; x1 += k0 + 5u;
#undef TF_R
  *o0 = x0; *o1 = x1;
}

// partitionable random_bits: bits[i] = o0 ^ o1 of tf(key, (0, i))
__device__ __forceinline__ float u01_at(uint32_t k0, uint32_t k1, uint32_t i) {
  uint32_t o0, o1;
  tf2x32(k0, k1, 0u, i, &o0, &o1);
  const uint32_t b = o0 ^ o1;
  const float f = __uint_as_float((b >> 9) | 0x3f800000u) - 1.0f;
  return fmaxf(0.0f, f);
}

__device__ __forceinline__ unsigned short f2bf(float f) {
  const uint32_t u = __float_as_uint(f);
  return (unsigned short)((u + 0x7fffu + ((u >> 16) & 1u)) >> 16);
}

__device__ __forceinline__ float bf2f(unsigned short h) {
  return __uint_as_float((uint32_t)h << 16);
}

// interp params for the LOGITS path (bf16 tolerance; same formula as exact path)
template <int SZ>
__device__ __forceinline__ void interp(float cx, float cy, int* off, float* wgt) {
  const float X = cx * (float)SZ - 0.5f, Y = cy * (float)SZ - 0.5f;
  const float x0f = floorf(X), y0f = floorf(Y);
  const float fx = X - x0f, fy = Y - y0f;
  const float wx0 = 1.0f - fx, wy0 = 1.0f - fy;
  const int x0 = (int)x0f, y0 = (int)y0f;
  const int x0c = min(max(x0, 0), SZ - 1), x1c = min(max(x0 + 1, 0), SZ - 1);
  const int y0c = min(max(y0, 0), SZ - 1), y1c = min(max(y0 + 1, 0), SZ - 1);
  const bool vx0 = (x0 >= 0) & (x0 <= SZ - 1), vx1 = (x0 >= -1) & (x0 <= SZ - 2);
  const bool vy0 = (y0 >= 0) & (y0 <= SZ - 1), vy1 = (y0 >= -1) & (y0 <= SZ - 2);
  off[0] = y0c * SZ + x0c; wgt[0] = (vy0 & vx0) ? wy0 * wx0 : 0.0f;
  off[1] = y0c * SZ + x1c; wgt[1] = (vy0 & vx1) ? wy0 * fx  : 0.0f;
  off[2] = y1c * SZ + x0c; wgt[2] = (vy1 & vx0) ? fy  * wx0 : 0.0f;
  off[3] = y1c * SZ + x1c; wgt[3] = (vy1 & vx1) ? fy  * fx  : 0.0f;
}

// ---- features transpose tile helpers (tile = 64ch x 64px, tt in [0,256)) ----
__device__ __forceinline__ void ftr_tile_load(const float* __restrict__ feats,
                                              int ti, int tt,
                                              unsigned short (*tile)[66]) {
  const int nn = ti >> 10, ct = (ti >> 8) & 3, pt = ti & 255;
  const int c0 = ct * 64, p0 = pt * 64;
  const float* src = feats + ((size_t)nn << 22);
#pragma unroll 4
  for (int k = 0; k < 16; ++k) {
    const int c = 4 * k + (tt >> 6);
    const int p = tt & 63;
    tile[p][c] = f2bf(src[((size_t)(c0 + c) << 14) + p0 + p]);
  }
}

__device__ __forceinline__ void ftr_tile_store(unsigned short* __restrict__ ftr,
                                               int ti, int tt,
                                               unsigned short (*tile)[66]) {
  const int nn = ti >> 10, ct = (ti >> 8) & 3, pt = ti & 255;
  const int c0 = ct * 64, p0 = pt * 64;
  const int p = tt >> 2, q = tt & 3;
  const int cb = q * 16;
  uint32_t w[8];
#pragma unroll
  for (int m = 0; m < 8; ++m)
    w[m] = (uint32_t)tile[p][cb + 2 * m] | ((uint32_t)tile[p][cb + 2 * m + 1] << 16);
  unsigned short* dst = ftr + ((((size_t)nn << 14) + p0 + p) << 8) + c0 + cb;
  *(uint4*)(dst)     = make_uint4(w[0], w[1], w[2], w[3]);
  *(uint4*)(dst + 8) = make_uint4(w[4], w[5], w[6], w[7]);
}

// ---- prep: ctr transpose [0,128) | weights [128,1028) | out0 copy [1028,1636) ----
__global__ __launch_bounds__(256) void prep(
    const float* __restrict__ coarse, float* __restrict__ ctr,
    const float* __restrict__ w0, const float* __restrict__ w1,
    const float* __restrict__ w2, const float* __restrict__ wpw,
    unsigned short* __restrict__ wbf, unsigned short* __restrict__ wpb,
    float* __restrict__ out0) {
  __shared__ float tile[CCH][257];
  const int b = blockIdx.x, t = threadIdx.x;
  if (b < 128) {
    const int nn = b >> 4, px0 = (b & 15) * 256;
    const float* src = coarse + (size_t)nn * (CCH * 4096) + px0;
#pragma unroll
    for (int c = 0; c < CCH; ++c) tile[c][t] = src[c * 4096 + t];
    __syncthreads();
    float v[CSTR];
#pragma unroll
    for (int c = 0; c < CCH; ++c) v[c] = tile[c][t];
    v[19] = 0.0f;
    float* dst = ctr + ((size_t)(nn << 12) + px0 + t) * CSTR;
#pragma unroll
    for (int k = 0; k < 5; ++k) {
      f32x4 x; x[0] = v[4*k]; x[1] = v[4*k+1]; x[2] = v[4*k+2]; x[3] = v[4*k+3];
      *(f32x4*)(dst + 4 * k) = x;
    }
  } else if (b < 1028) {
    const int i = (b - 128) * 256 + t;
    if (i < 3 * 256 * KP) {
      const int L = i / (256 * KP);
      const int rem = i - L * (256 * KP);
      const int o = rem / KP, k = rem - o * KP;
      const float* W = (L == 0) ? w0 : (L == 1) ? w1 : w2;
      wbf[i] = (k < FIN) ? f2bf(W[o * FIN + k]) : (unsigned short)0;
    } else {
      const int j = i - 3 * 256 * KP;
      const int o = j / KP, k = j - o * KP;
      wpb[j] = (o < CCH && k < FIN) ? f2bf(wpw[o * FIN + k]) : (unsigned short)0;
    }
  } else {
    // coarse passthrough: 155648 float4 = 622592 f32 (exact)
    const int i4 = (b - 1028) * 256 + t;
    ((float4*)out0)[i4] = ((const float4*)coarse)[i4];
  }
}

// ---- unc_keys [0,2048) | ftr transpose tiles [2048, 2048+ntiles) ----
__global__ __launch_bounds__(256) void unc_tr(
    const float* __restrict__ ctr, unsigned long long* __restrict__ keys,
    const float* __restrict__ feats, unsigned short* __restrict__ ftr,
    uint32_t k1a, uint32_t k1b, int tile0, int use_tr) {
  __shared__ unsigned short tile[64][66];
  const int bid = blockIdx.x, t = threadIdx.x;
  if (bid < 2048) {
    // ---- uncertainty -> sortable keys (EXACT: contract-off, left-assoc) ----
    const int tid = bid * 256 + t;
    const int nn = tid >> 16, s = tid & (SORT_M - 1);
    if (s >= NSAMP) { keys[tid] = 0xFFFFFFFFFFFFFFFFull; return; }
    const uint32_t ci = (uint32_t)(((unsigned)nn * NSAMP + (unsigned)s) * 2);
    const float cx = u01_at(k1a, k1b, ci);
    const float cy = u01_at(k1a, k1b, ci + 1);
    const float X = cx * 64.0f - 0.5f, Y = cy * 64.0f - 0.5f;
    const float x0f = floorf(X), y0f = floorf(Y);
    const float fx = X - x0f, fy = Y - y0f;
    const float wx0 = 1.0f - fx, wy0 = 1.0f - fy;
    const int x0 = (int)x0f, y0 = (int)y0f;
    const int x0c = min(max(x0, 0), 63), x1c = min(max(x0 + 1, 0), 63);
    const int y0c = min(max(y0, 0), 63), y1c = min(max(y0 + 1, 0), 63);
    const bool vx0 = (x0 >= 0) & (x0 <= 63), vx1 = (x0 >= -1) & (x0 <= 62);
    const bool vy0 = (y0 >= 0) & (y0 <= 63), vy1 = (y0 >= -1) & (y0 <= 62);
    const float w00 = (vy0 & vx0) ? wy0 * wx0 : 0.0f;
    const float w01 = (vy0 & vx1) ? wy0 * fx  : 0.0f;
    const float w10 = (vy1 & vx0) ? fy  * wx0 : 0.0f;
    const float w11 = (vy1 & vx1) ? fy  * fx  : 0.0f;
    const float* rb = ctr + ((size_t)nn << 12) * CSTR;
    const float* r0 = rb + (size_t)(y0c * 64 + x0c) * CSTR;
    const float* r1 = rb + (size_t)(y0c * 64 + x1c) * CSTR;
    const float* r2 = rb + (size_t)(y1c * 64 + x0c) * CSTR;
    const float* r3 = rb + (size_t)(y1c * 64 + x1c) * CSTR;
    float m1 = -3.402823466e38f, m2 = -3.402823466e38f;
#pragma unroll
    for (int k = 0; k < 5; ++k) {
      const f32x4 x0v = *(const f32x4*)(r0 + 4 * k);
      const f32x4 x1v = *(const f32x4*)(r1 + 4 * k);
      const f32x4 x2v = *(const f32x4*)(r2 + 4 * k);
      const f32x4 x3v = *(const f32x4*)(r3 + 4 * k);
#pragma unroll
      for (int e = 0; e < 4; ++e) {
        const int c = 4 * k + e;
        if (c < CCH) {
          const float v = ((x0v[e] * w00 + x1v[e] * w01) + x2v[e] * w10) + x3v[e] * w11;
          if (v > m1) { m2 = m1; m1 = v; } else if (v > m2) { m2 = v; }
        }
      }
    }
    const float unc = m2 - m1;
    const uint32_t b = __float_as_uint(unc);
    const uint32_t asc = (b & 0x80000000u) ? ~b : (b | 0x80000000u);
    keys[tid] = ((unsigned long long)(~asc) << 32) | (uint32_t)s;
  } else {
    if (!use_tr) return;
    const int ti = tile0 + (bid - 2048);
    ftr_tile_load(feats, ti, t, tile);
    __syncthreads();
    ftr_tile_store(ftr, ti, t, tile);
  }
}

// ---- bitonic local sort [0,64) | transpose 4-tile packs [64,...) ----
__global__ __launch_bounds__(1024) void bitonic_local_tr(
    unsigned long long* __restrict__ keys,
    const float* __restrict__ feats, unsigned short* __restrict__ ftr,
    int tile0, int use_tr) {
  __shared__ unsigned long long s[CHUNK];   // 64 KiB (aliased by transpose)
  const int b = blockIdx.x, t = threadIdx.x;
  if (b < 64) {
    unsigned long long* a = keys + (size_t)b * CHUNK;
    const unsigned gbase = (unsigned)(b * CHUNK) & (SORT_M - 1);
    for (int i = t; i < CHUNK; i += 1024) s[i] = a[i];
    __syncthreads();
    for (int k = 2; k <= CHUNK; k <<= 1) {
      for (int j = k >> 1; j > 0; j >>= 1) {
        for (int pid = t; pid < CHUNK / 2; pid += 1024) {
          const int i = ((pid & ~(j - 1)) << 1) | (pid & (j - 1));
          const int l = i | j;
          const bool up = (((gbase + i) & k) == 0);
          const unsigned long long x = s[i], y = s[l];
          if ((x > y) == up) { s[i] = y; s[l] = x; }
        }
        __syncthreads();
      }
    }
    for (int i = t; i < CHUNK; i += 1024) a[i] = s[i];
  } else {
    if (!use_tr) return;
    unsigned short (*tp)[66] =
        (unsigned short (*)[66])((char*)s + (size_t)(t >> 8) * (64 * 66 * 2));
    const int ti = tile0 + (b - 64) * 4 + (t >> 8);
    const int tt = t & 255;
    ftr_tile_load(feats, ti, tt, tp);
    __syncthreads();
    ftr_tile_store(ftr, ti, tt, tp);
  }
}

// ---- global compare-exchange [0,nsort) | transpose tiles [nsort,...) ----
__global__ __launch_bounds__(256) void bitonic_global_tr(
    unsigned long long* __restrict__ keys, int k, int j, int ppb_shift, int nsort,
    const float* __restrict__ feats, unsigned short* __restrict__ ftr,
    int tile0, int use_tr) {
  __shared__ unsigned short tile[64][66];
  const int bb = blockIdx.x, tt = threadIdx.x;
  if (bb < nsort) {
    const int t = bb * 256 + tt;
    const int b = t >> ppb_shift, pid = t & ((1 << ppb_shift) - 1);
    const int i = ((pid & ~(j - 1)) << 1) | (pid & (j - 1));
    const int l = i | j;
    const bool up = ((i & k) == 0);
    unsigned long long* a = keys + ((size_t)b << 16);
    const unsigned long long x = a[i], y = a[l];
    if ((x > y) == up) { a[i] = y; a[l] = x; }
  } else {
    if (!use_tr) return;
    const int ti = tile0 + (bb - nsort);
    ftr_tile_load(feats, ti, tt, tile);
    __syncthreads();
    ftr_tile_store(ftr, ti, tt, tile);
  }
}

// ---- bitonic finish [0,64) | transpose 4-tile packs [64,...) ----
__global__ __launch_bounds__(1024) void bitonic_finish_tr(
    unsigned long long* __restrict__ keys, int k,
    const float* __restrict__ feats, unsigned short* __restrict__ ftr,
    int tile0, int use_tr) {
  __shared__ unsigned long long s[CHUNK];
  const int b = blockIdx.x, t = threadIdx.x;
  if (b < 64) {
    unsigned long long* a = keys + (size_t)b * CHUNK;
    const unsigned gi0 = (unsigned)(b * CHUNK) & (SORT_M - 1);
    for (int i = t; i < CHUNK; i += 1024) s[i] = a[i];
    __syncthreads();
    const bool up = ((gi0 & k) == 0);
    for (int j = CHUNK >> 1; j > 0; j >>= 1) {
      for (int pid = t; pid < CHUNK / 2; pid += 1024) {
        const int i = ((pid & ~(j - 1)) << 1) | (pid & (j - 1));
        const int l = i | j;
        const unsigned long long x = s[i], y = s[l];
        if ((x > y) == up) { s[i] = y; s[l] = x; }
      }
      __syncthreads();
    }
    for (int i = t; i < CHUNK; i += 1024) a[i] = s[i];
  } else {
    if (!use_tr) return;
    unsigned short (*tp)[66] =
        (unsigned short (*)[66])((char*)s + (size_t)(t >> 8) * (64 * 66 * 2));
    const int ti = tile0 + (b - 64) * 4 + (t >> 8);
    const int tt = t & 255;
    ftr_tile_load(feats, ti, tt, tp);
    __syncthreads();
    ftr_tile_store(ftr, ti, tt, tp);
  }
}

// ---- finish j<=4096 on lowest-16K chunks + write coords | transpose packs ----
__global__ __launch_bounds__(1024) void finlow_tr(
    const unsigned long long* __restrict__ keys, float* __restrict__ outc,
    uint32_t k1a, uint32_t k1b, uint32_t k2a, uint32_t k2b,
    const float* __restrict__ feats, unsigned short* __restrict__ ftr,
    int tile0, int use_tr) {
  __shared__ unsigned long long s[CHUNK];
  const int b = blockIdx.x, t = threadIdx.x;
  if (b < 16) {
    const int nn = b >> 1, half = b & 1;
    const unsigned long long* a = keys + ((size_t)nn << 16) + half * CHUNK;
    for (int i = t; i < CHUNK; i += 1024) s[i] = a[i];
    __syncthreads();
    for (int j = CHUNK >> 1; j > 0; j >>= 1) {
      for (int pid = t; pid < CHUNK / 2; pid += 1024) {
        const int i = ((pid & ~(j - 1)) << 1) | (pid & (j - 1));
        const int l = i | j;
        const unsigned long long x = s[i], y = s[l];
        if (x > y) { s[i] = y; s[l] = x; }
      }
      __syncthreads();
    }
    const int pb = half * CHUNK;
    for (int q = t; q < CHUNK; q += 1024) {
      const int p = pb + q;
      float cx, cy;
      if (p < NIMP) {
        const unsigned idx = (unsigned)(s[q] & 0xFFFFFFFFu);
        const uint32_t ci = ((unsigned)nn * NSAMP + idx) * 2;
        cx = u01_at(k1a, k1b, ci);
        cy = u01_at(k1a, k1b, ci + 1);
      } else {
        const uint32_t ri = ((unsigned)nn * NRAND + (unsigned)(p - NIMP)) * 2;
        cx = u01_at(k2a, k2b, ri);
        cy = u01_at(k2a, k2b, ri + 1);
      }
      float* o = outc + (((size_t)nn << 14) + p) * 2;
      o[0] = cx; o[1] = cy;
    }
  } else {
    if (!use_tr) return;
    unsigned short (*tp)[66] =
        (unsigned short (*)[66])((char*)s + (size_t)(t >> 8) * (64 * 66 * 2));
    const int ti = tile0 + (b - 16) * 4 + (t >> 8);
    const int tt = t & 255;
    ftr_tile_load(feats, ti, tt, tp);
    __syncthreads();
    ftr_tile_store(ftr, ti, tt, tp);
  }
}

// ---------------- fused sample + bf16-MFMA MLP + head (r10 proven, XROW 640) ----
template <int USE_TR>
__global__ __launch_bounds__(512, 4) void fused_mfma(
    const float* __restrict__ coarse, const float* __restrict__ feats,
    const unsigned short* __restrict__ ftr, const float* __restrict__ ctr,
    const float* __restrict__ b0, const float* __restrict__ b1,
    const float* __restrict__ b2, const float* __restrict__ bp,
    const unsigned short* __restrict__ wbf, const unsigned short* __restrict__ wpb,
    const float* __restrict__ pc, float* __restrict__ outl) {
  __shared__ __align__(16) unsigned short xp[TP * (XROW / 2)];   // 40960 B

  const int t = threadIdx.x;
  // XCD swizzle: XCD x serves batch x's ftr slab (8 MB vs 4 MB L2).
  const int bid = ((int)blockIdx.x & 7) * 256 + ((int)blockIdx.x >> 3);
  const int nn = bid >> 8;
  const int pbase = (bid & 255) * TP;

  int offF[4]; float wgtF[4];     // fine interp of point t>>3
  int offC[4]; float wgtC[4];     // coarse interp of point t&63
  int offFc[4]; float wgtFc[4];   // fine interp of point t&63 (fallback only)
  {
    const float2 c = *(const float2*)(pc + ((size_t)nn * NPTS + pbase + (t >> 3)) * 2);
    interp<128>(c.x, c.y, offF, wgtF);
  }
  {
    const float2 c = *(const float2*)(pc + ((size_t)nn * NPTS + pbase + (t & 63)) * 2);
    interp<64>(c.x, c.y, offC, wgtC);
    if (!USE_TR) interp<128>(c.x, c.y, offFc, wgtFc);
  }

  if (USE_TR) {
    // ---- fine gather from transposed bf16: 8 thr/point, 32 ch each ----
    const int p = t >> 3, q = t & 7;
    const unsigned short* base = ftr + ((size_t)nn << 22) + q * 32;
    const unsigned short* n0 = base + ((size_t)offF[0] << 8);
    const unsigned short* n1 = base + ((size_t)offF[1] << 8);
    const unsigned short* n2 = base + ((size_t)offF[2] << 8);
    const unsigned short* n3 = base + ((size_t)offF[3] << 8);
    const float g0 = wgtF[0], g1 = wgtF[1], g2 = wgtF[2], g3 = wgtF[3];
    const unsigned swzp = (unsigned)(p & 7) << 4;
#pragma unroll
    for (int m = 0; m < 4; ++m) {
      const bf16x8 a = *(const bf16x8*)(n0 + m * 8);
      const bf16x8 bq = *(const bf16x8*)(n1 + m * 8);
      const bf16x8 c = *(const bf16x8*)(n2 + m * 8);
      const bf16x8 d = *(const bf16x8*)(n3 + m * 8);
      uint32_t u[4];
#pragma unroll
      for (int e = 0; e < 4; ++e) {
        float v0 = fmaf(bf2f((unsigned short)a[2 * e]), g0,
                   fmaf(bf2f((unsigned short)bq[2 * e]), g1,
                   fmaf(bf2f((unsigned short)c[2 * e]), g2,
                        bf2f((unsigned short)d[2 * e]) * g3)));
        float v1 = fmaf(bf2f((unsigned short)a[2 * e + 1]), g0,
                   fmaf(bf2f((unsigned short)bq[2 * e + 1]), g1,
                   fmaf(bf2f((unsigned short)c[2 * e + 1]), g2,
                        bf2f((unsigned short)d[2 * e + 1]) * g3)));
        u[e] = (uint32_t)f2bf(v0) | ((uint32_t)f2bf(v1) << 16);
      }
      *(uint4*)((char*)xp + p * XROW + (((unsigned)((q * 32 + m * 8) * 2)) ^ swzp)) =
          make_uint4(u[0], u[1], u[2], u[3]);
    }
    // ---- coarse channels 256..287 from ctr: one thread per point ----
    if (t < TP) {
      const int pp = t;
      const float* rb = ctr + ((size_t)nn << 12) * CSTR;
      const float* r0 = rb + (size_t)offC[0] * CSTR;
      const float* r1 = rb + (size_t)offC[1] * CSTR;
      const float* r2 = rb + (size_t)offC[2] * CSTR;
      const float* r3 = rb + (size_t)offC[3] * CSTR;
      const float h0 = wgtC[0], h1 = wgtC[1], h2 = wgtC[2], h3 = wgtC[3];
      unsigned short hs[32];
#pragma unroll
      for (int k = 0; k < 5; ++k) {
        const f32x4 x0v = *(const f32x4*)(r0 + 4 * k);
        const f32x4 x1v = *(const f32x4*)(r1 + 4 * k);
        const f32x4 x2v = *(const f32x4*)(r2 + 4 * k);
        const f32x4 x3v = *(const f32x4*)(r3 + 4 * k);
#pragma unroll
        for (int e = 0; e < 4; ++e) {
          const int c = 4 * k + e;
          if (c < CCH)
            hs[c] = f2bf(fmaf(x0v[e], h0, fmaf(x1v[e], h1,
                         fmaf(x2v[e], h2, x3v[e] * h3))));
        }
      }
#pragma unroll
      for (int c = CCH; c < 32; ++c) hs[c] = 0;
      const unsigned swzc = (unsigned)(pp & 7) << 4;
#pragma unroll
      for (int k = 0; k < 4; ++k) {
        uint4 u;
        u.x = (uint32_t)hs[8*k]   | ((uint32_t)hs[8*k+1] << 16);
        u.y = (uint32_t)hs[8*k+2] | ((uint32_t)hs[8*k+3] << 16);
        u.z = (uint32_t)hs[8*k+4] | ((uint32_t)hs[8*k+5] << 16);
        u.w = (uint32_t)hs[8*k+6] | ((uint32_t)hs[8*k+7] << 16);
        *(uint4*)((char*)xp + pp * XROW + (((unsigned)(512 + 16 * k)) ^ swzc)) = u;
      }
    }
  } else {
    // ---- fallback: scalar gather of all channels from original layouts ----
    for (int i = t; i < (KP / 2) * TP; i += 512) {
      const int p = i & (TP - 1);
      const int c0 = (i >> 6) * 2;
      float v0 = 0.0f, v1 = 0.0f;
      if (c0 < FCH) {
        const float* fb0 = feats + ((size_t)nn << 22) + ((size_t)c0 << 14);
        const float* fb1 = fb0 + 16384;
        v0 = ((fb0[offFc[0]] * wgtFc[0] + fb0[offFc[1]] * wgtFc[1])
             + fb0[offFc[2]] * wgtFc[2]) + fb0[offFc[3]] * wgtFc[3];
        v1 = ((fb1[offFc[0]] * wgtFc[0] + fb1[offFc[1]] * wgtFc[1])
             + fb1[offFc[2]] * wgtFc[2]) + fb1[offFc[3]] * wgtFc[3];
      } else if (c0 < FIN) {
        const float* cb0 = coarse + (size_t)nn * (CCH * 4096) + (size_t)(c0 - FCH) * 4096;
        v0 = ((cb0[offC[0]] * wgtC[0] + cb0[offC[1]] * wgtC[1])
             + cb0[offC[2]] * wgtC[2]) + cb0[offC[3]] * wgtC[3];
        if (c0 + 1 < FIN) {
          const float* cb1 = cb0 + 4096;
          v1 = ((cb1[offC[0]] * wgtC[0] + cb1[offC[1]] * wgtC[1])
               + cb1[offC[2]] * wgtC[2]) + cb1[offC[3]] * wgtC[3];
        }
      }
      const uint32_t u = (uint32_t)f2bf(v0) | ((uint32_t)f2bf(v1) << 16);
      *(uint32_t*)((char*)xp + p * XROW + (((unsigned)(c0 * 2)) ^ ((unsigned)(p & 7) << 4))) = u;
    }
  }

  const int lane = t & 63, wave = t >> 6;
  const int wm = wave & 3, wn = wave >> 2;
  const int l15 = lane & 15, g = lane >> 4;
  const unsigned swz = (unsigned)(l15 & 7) << 4;
  const char* xpB = (const char*)xp;

#pragma unroll    // static L => weight/bias pointers resolved at compile time
  for (int L = 0; L < 3; ++L) {
    __syncthreads();   // xp inputs visible (gather for L=0, epilogue for L>0)
    const float* Bv = (L == 0) ? b0 : (L == 1) ? b1 : b2;
    const unsigned short* wL = wbf + (size_t)L * (256 * KP);
    const unsigned short* wbase = wL + (size_t)(wm * 64 + l15) * KP + g * 8;

    f32x4 acc[4][2];
#pragma unroll
    for (int mt = 0; mt < 4; ++mt)
#pragma unroll
      for (int nt = 0; nt < 2; ++nt) acc[mt][nt] = (f32x4)(0.0f);

    // 1-deep weight prefetch: a-regs for ks+1 issued during ks's MFMAs.
    bf16x8 a0 = *(const bf16x8*)(wbase + 0 * 16 * KP);
    bf16x8 a1 = *(const bf16x8*)(wbase + 1 * 16 * KP);
    bf16x8 a2 = *(const bf16x8*)(wbase + 2 * 16 * KP);
    bf16x8 a3 = *(const bf16x8*)(wbase + 3 * 16 * KP);
    for (int ks = 0; ks < 9; ++ks) {
      const bf16x8 c0v = a0, c1v = a1, c2v = a2, c3v = a3;
      if (ks < 8) {
        a0 = *(const bf16x8*)(wbase + 0 * 16 * KP + (ks + 1) * 32);
        a1 = *(const bf16x8*)(wbase + 1 * 16 * KP + (ks + 1) * 32);
        a2 = *(const bf16x8*)(wbase + 2 * 16 * KP + (ks + 1) * 32);
        a3 = *(const bf16x8*)(wbase + 3 * 16 * KP + (ks + 1) * 32);
      }
      const unsigned kb = (unsigned)(ks * 64 + g * 16) ^ swz;
      const bf16x8 q0 = *(const bf16x8*)(xpB + (wn * 32 + 0 + l15) * XROW + kb);
      const bf16x8 q1 = *(const bf16x8*)(xpB + (wn * 32 + 16 + l15) * XROW + kb);
      acc[0][0] = __builtin_amdgcn_mfma_f32_16x16x32_bf16(c0v, q0, acc[0][0], 0, 0, 0);
      acc[1][0] = __builtin_amdgcn_mfma_f32_16x16x32_bf16(c1v, q0, acc[1][0], 0, 0, 0);
      acc[2][0] = __builtin_amdgcn_mfma_f32_16x16x32_bf16(c2v, q0, acc[2][0], 0, 0, 0);
      acc[3][0] = __builtin_amdgcn_mfma_f32_16x16x32_bf16(c3v, q0, acc[3][0], 0, 0, 0);
      acc[0][1] = __builtin_amdgcn_mfma_f32_16x16x32_bf16(c0v, q1, acc[0][1], 0, 0, 0);
      acc[1][1] = __builtin_amdgcn_mfma_f32_16x16x32_bf16(c1v, q1, acc[1][1], 0, 0, 0);
      acc[2][1] = __builtin_amdgcn_mfma_f32_16x16x32_bf16(c2v, q1, acc[2][1], 0, 0, 0);
      acc[3][1] = __builtin_amdgcn_mfma_f32_16x16x32_bf16(c3v, q1, acc[3][1], 0, 0, 0);
    }
    __syncthreads();   // all reads of xp done before overwrite

#pragma unroll
    for (int mt = 0; mt < 4; ++mt) {
      const int ch0 = wm * 64 + mt * 16 + (g << 2);
      const float4 bv = *(const float4*)(Bv + ch0);
#pragma unroll
      for (int nt = 0; nt < 2; ++nt) {
        const int p = wn * 32 + nt * 16 + l15;
        const f32x4 v = acc[mt][nt];
        const unsigned short h0 = f2bf(fmaxf(v[0] + bv.x, 0.0f));
        const unsigned short h1 = f2bf(fmaxf(v[1] + bv.y, 0.0f));
        const unsigned short h2 = f2bf(fmaxf(v[2] + bv.z, 0.0f));
        const unsigned short h3 = f2bf(fmaxf(v[3] + bv.w, 0.0f));
        uint2 u;
        u.x = (uint32_t)h0 | ((uint32_t)h1 << 16);
        u.y = (uint32_t)h2 | ((uint32_t)h3 << 16);
        *(uint2*)((char*)xp + p * XROW + (((unsigned)(ch0 * 2)) ^ swz)) = u;
      }
    }
  }
  __syncthreads();   // layer-2 output (head input) visible

  // ---- head: 8 (mt,nt) pairs, one per wave: mt = w>>2 (0..1), nt = w&3 ----
  const int hmt = wave >> 2, hnt = wave & 3;
  const unsigned short* hbase = wpb + (size_t)(hmt * 16 + l15) * KP + g * 8;
  f32x4 hacc = (f32x4)(0.0f);
  for (int ks = 0; ks < 9; ++ks) {
    const unsigned kb = (unsigned)(ks * 64 + g * 16) ^ swz;
    const bf16x8 ha = *(const bf16x8*)(hbase + ks * 32);
    const bf16x8 hb = *(const bf16x8*)(xpB + (hnt * 16 + l15) * XROW + kb);
    hacc = __builtin_amdgcn_mfma_f32_16x16x32_bf16(ha, hb, hacc, 0, 0, 0);
  }
  const int p = pbase + hnt * 16 + l15;
#pragma unroll
  for (int j = 0; j < 4; ++j) {
    const int ch = hmt * 16 + (g << 2) + j;
    if (ch < CCH)
      outl[((size_t)nn * CCH + ch) * NPTS + p] = hacc[j] + bp[ch];
  }
}

// ---------------- launcher ----------------
extern "C" void kernel_launch(void* const* d_in, const int* in_sizes, int n_in,
                              void* d_out, int out_size, void* d_ws, size_t ws_size,
                              hipStream_t stream) {
  const float* coarse = (const float*)d_in[0];
  const float* feats  = (const float*)d_in[1];
  const float* w0 = (const float*)d_in[2]; const float* b0 = (const float*)d_in[3];
  const float* w1 = (const float*)d_in[4]; const float* b1 = (const float*)d_in[5];
  const float* w2 = (const float*)d_in[6]; const float* b2 = (const float*)d_in[7];
  const float* wp = (const float*)d_in[8]; const float* bp = (const float*)d_in[9];

  float* out0 = (float*)d_out;
  float* outL = out0 + 622592;
  float* outC = outL + 2490368;

  unsigned long long* keys = (unsigned long long*)d_ws;            // 4 MiB
  unsigned short* wbf = (unsigned short*)((char*)d_ws + WBF_OFF);  // 450 KiB
  unsigned short* wpb = wbf + 3 * 256 * KP;
  float* ctr = (float*)((char*)d_ws + CTR_OFF);                    // 2.5 MiB
  unsigned short* ftr = (unsigned short*)((char*)d_ws + FTR_OFF);  // 64 MiB
  const int use_tr = (ws_size >= (size_t)FTR_OFF + FTR_BYTES) ? 1 : 0;

  // host-side split of jax.random.key(7) = (0,7): key_i = tf(key, (0,i))
  uint32_t k1a, k1b, k2a, k2b;
  tf2x32(0u, 7u, 0u, 0u, &k1a, &k1b);
  tf2x32(0u, 7u, 0u, 1u, &k2a, &k2b);

  // ctr transpose + weight convert + out0 passthrough (one dispatch)
  prep<<<1636, 256, 0, stream>>>(coarse, ctr, w0, w1, w2, wp, wbf, wpb, out0);

  // uncertainty keys; ftr transpose tiles ride along in every dispatch below.
  // Tile budget: unc 1024 | local 768 | 6 globals x896 | 2 finishes x448 |
  // finlow 128  == 8192 total.
  const int NT = use_tr ? 1 : 0;
  unc_tr<<<2048 + NT * 1024, 256, 0, stream>>>(ctr, keys, feats, ftr,
                                               k1a, k1b, 0, use_tr);
  bitonic_local_tr<<<64 + NT * 192, 1024, 0, stream>>>(keys, feats, ftr, 1024, use_tr);
  bitonic_global_tr<<<1024 + NT * 896, 256, 0, stream>>>(keys, 16384, 8192, 15, 1024,
                                                         feats, ftr, 1792, use_tr);
  bitonic_finish_tr<<<64 + NT * 112, 1024, 0, stream>>>(keys, 16384, feats, ftr,
                                                        2688, use_tr);
  bitonic_global_tr<<<1024 + NT * 896, 256, 0, stream>>>(keys, 32768, 16384, 15, 1024,
                                                         feats, ftr, 3136, use_tr);
  bitonic_global_tr<<<1024 + NT * 896, 256, 0, stream>>>(keys, 32768, 8192, 15, 1024,
                                                         feats, ftr, 4032, use_tr);
  bitonic_finish_tr<<<64 + NT * 112, 1024, 0, stream>>>(keys, 32768, feats, ftr,
                                                        4928, use_tr);
  bitonic_global_tr<<<1024 + NT * 896, 256, 0, stream>>>(keys, 65536, 32768, 15, 1024,
                                                         feats, ftr, 5376, use_tr);
  bitonic_global_tr<<<512 + NT * 896, 256, 0, stream>>>(keys, 65536, 16384, 14, 512,
                                                        feats, ftr, 6272, use_tr);
  bitonic_global_tr<<<256 + NT * 896, 256, 0, stream>>>(keys, 65536, 8192, 13, 256,
                                                        feats, ftr, 7168, use_tr);
  finlow_tr<<<16 + NT * 32, 1024, 0, stream>>>(keys, outC, k1a, k1b, k2a, k2b,
                                               feats, ftr, 8064, use_tr);

  if (use_tr)
    fused_mfma<1><<<2048, 512, 0, stream>>>(coarse, feats, ftr, ctr, b0, b1, b2,
                                            bp, wbf, wpb, outC, outL);
  else
    fused_mfma<0><<<2048, 512, 0, stream>>>(coarse, feats, ftr, ctr, b0, b1, b2,
                                            bp, wbf, wpb, outC, outL);
}